// Round 1
// baseline (269.723 us; speedup 1.0000x reference)
//
#include <hip/hip_runtime.h>
#include <hip/hip_bf16.h>

// LorentzEquivariantAdapter fused kernel, MI355X gfx950.
// Pipeline per token (B*N=32768, D=1024, R=48, MV=16, W=1):
//   LN -> gelu(h@w_down^T) -> w_to_mv -> grade-scale(+bias) -> gelu(@w_from_mv^T) -> @w_up^T -> x + scale*h
// Strategy: bf16 MFMA (16x16x32) for the two big GEMMs, fp32 VALU for the tiny middle,
// x kept in LDS as bf16 for the residual (single HBM read of x).

typedef __attribute__((ext_vector_type(8))) short short8;   // 8 bf16 = one MFMA A/B fragment
typedef __attribute__((ext_vector_type(4))) short short4b;  // 4 bf16 = 8B store
typedef __attribute__((ext_vector_type(4))) float float4a;  // MFMA accumulator

#define TOKENS_PER_BLOCK 16
#define NTOK 32768
#define D 1024
#define R 48

__device__ __forceinline__ short f2bf(float x) {
    unsigned u = __float_as_uint(x);
    unsigned r = u + 0x7FFFu + ((u >> 16) & 1u);   // RNE
    return (short)(r >> 16);
}
__device__ __forceinline__ float bf2f(short s) {
    return __uint_as_float(((unsigned)(unsigned short)s) << 16);
}
__device__ __forceinline__ float gelu_exact(float v) {
    return 0.5f * v * (1.0f + erff(v * 0.70710678118654752f));
}

// ---- weight prep: fp32 -> bf16, rearranged into MFMA B-fragment lane order ----
// B-fragment (16x16x32): lane l holds B[k = (l>>4)*8 + j][n = l&15], j=0..7.
// wdn_b: GEMM1 B = w_down[r][d]  (n=r in 3 col-blocks, k=d in 32 K-tiles)
// wup_b: GEMM2 B = w_up[d][r]    (n=d in 64 col-blocks, k=r padded 48->64, 2 K-tiles)
__global__ void prep_weights(const float* __restrict__ wdn_f, const float* __restrict__ wup_f,
                             short* __restrict__ wdn_b, short* __restrict__ wup_b) {
    int o = blockIdx.x * 256 + threadIdx.x;
    if (o < 49152) {
        int j = o & 7, lane = (o >> 3) & 63, kt = (o >> 9) & 31, cb = o >> 14;
        int r = cb * 16 + (lane & 15);
        int d = kt * 32 + (lane >> 4) * 8 + j;
        wdn_b[o] = f2bf(wdn_f[r * 1024 + d]);
    } else {
        int o2 = o - 49152;
        if (o2 < 65536) {
            int j = o2 & 7, lane = (o2 >> 3) & 63, kt = (o2 >> 9) & 1, cb = o2 >> 10;
            int dcol = cb * 16 + (lane & 15);
            int r = kt * 32 + (lane >> 4) * 8 + j;
            wup_b[o2] = (r < 48) ? f2bf(wup_f[dcol * 48 + r]) : (short)0;
        }
    }
}

__launch_bounds__(256, 2)
__global__ void adapter_main(const float* __restrict__ x, const float* __restrict__ gamma,
                             const float* __restrict__ beta, const float* __restrict__ w_to_mv,
                             const float* __restrict__ w_equi, const float* __restrict__ b_equi,
                             const float* __restrict__ w_from_mv, const float* __restrict__ scale_p,
                             const short* __restrict__ wdn_b, const short* __restrict__ wup_b,
                             float* __restrict__ out) {
    // LDS: 78,080 B total -> 2 blocks/CU
    __shared__ __align__(16) short hln[16][1032];      // LN output bf16, +8 shorts pad => conflict-free A b128 reads
    __shared__ __align__(16) short xsh[16][1024];      // raw x as bf16 (residual)
    __shared__ __align__(16) float ypart[2][16][48];   // GEMM1 K-split partials
    __shared__ __align__(16) float ybuf[16][48];       // gelu(down) fp32
    __shared__ __align__(16) float mvbuf[16][16];      // multivectors fp32
    __shared__ __align__(16) short zbuf[1024];         // GEMM2 A-fragment order, K padded 48->64

    const int tid  = threadIdx.x;
    const int lane = tid & 63;
    const int w    = tid >> 6;          // wave id 0..3
    const int q    = lane >> 4;         // MFMA quad
    const int m    = lane & 15;         // MFMA row/col within tile
    const long token0 = (long)blockIdx.x * TOKENS_PER_BLOCK;

    // zero the K-padding region of zbuf (k=48..63 -> zbuf[768..1023])
    zbuf[768 + tid] = 0;

    // ---------------- Phase 0: LayerNorm -> hln(bf16), x -> xsh(bf16) ----------------
    {
        const float4* g4 = (const float4*)gamma;
        const float4* b4 = (const float4*)beta;
        for (int t = 0; t < 4; ++t) {
            int tok = w * 4 + t;
            const float4* xr = (const float4*)(x + (token0 + tok) * D);
            float4 v[4];
            float s1 = 0.f, s2 = 0.f;
#pragma unroll
            for (int i = 0; i < 4; ++i) {
                v[i] = xr[lane + 64 * i];     // element d = 4*lane + 256*i + {0..3}
                s1 += v[i].x + v[i].y + v[i].z + v[i].w;
                s2 += v[i].x * v[i].x + v[i].y * v[i].y + v[i].z * v[i].z + v[i].w * v[i].w;
            }
#pragma unroll
            for (int off = 32; off; off >>= 1) {
                s1 += __shfl_xor(s1, off);
                s2 += __shfl_xor(s2, off);
            }
            float mu = s1 * (1.0f / 1024.0f);
            float var = fmaf(-mu, mu, s2 * (1.0f / 1024.0f));
            float rs = rsqrtf(var + 1e-5f);
#pragma unroll
            for (int i = 0; i < 4; ++i) {
                int d0 = 4 * lane + 256 * i;
                float4 g = g4[lane + 64 * i];
                float4 b = b4[lane + 64 * i];
                float h0 = fmaf((v[i].x - mu) * rs, g.x, b.x);
                float h1 = fmaf((v[i].y - mu) * rs, g.y, b.y);
                float h2 = fmaf((v[i].z - mu) * rs, g.z, b.z);
                float h3 = fmaf((v[i].w - mu) * rs, g.w, b.w);
                short4b hs = {f2bf(h0), f2bf(h1), f2bf(h2), f2bf(h3)};
                *(short4b*)&hln[tok][d0] = hs;
                short4b xs = {f2bf(v[i].x), f2bf(v[i].y), f2bf(v[i].z), f2bf(v[i].w)};
                *(short4b*)&xsh[tok][d0] = xs;
            }
        }
    }
    __syncthreads();

    // ---------------- GEMM1: y[16 tok][48 r] = hln @ w_down^T (bf16 MFMA) ----------------
    // 6 jobs = 3 col-blocks x 2 K-halves, distributed over 4 waves.
#pragma unroll
    for (int rep = 0; rep < 2; ++rep) {
        int jid = w + rep * 4;
        if (jid < 6) {
            int cb = jid % 3, kh = jid / 3;
            float4a acc = {0.f, 0.f, 0.f, 0.f};
            const short* bptr = wdn_b + ((cb * 32 + kh * 16) * 64 + lane) * 8;
            const short* aptr = &hln[m][kh * 16 * 32 + q * 8];
#pragma unroll
            for (int kt = 0; kt < 16; ++kt) {
                short8 a = *(const short8*)(aptr + kt * 32);
                short8 b = *(const short8*)(bptr + kt * 512);
                acc = __builtin_amdgcn_mfma_f32_16x16x32_bf16(a, b, acc, 0, 0, 0);
            }
#pragma unroll
            for (int i = 0; i < 4; ++i) ypart[kh][q * 4 + i][cb * 16 + m] = acc[i];
        }
    }
    __syncthreads();

    // ---------------- Middle (fp32 VALU) ----------------
    // A: reduce K-halves + exact GELU
#pragma unroll
    for (int k = 0; k < 3; ++k) {
        int it = tid + k * 256;           // 768 items = 16 tok x 48 r
        int tt = it / 48, r = it - tt * 48;
        float s = ypart[0][tt][r] + ypart[1][tt][r];
        ybuf[tt][r] = gelu_exact(s);
    }
    __syncthreads();
    // B: mv[tt][j] = sum_r w_to_mv[j][r]*y[tt][r]; grade scale; scalar bias
    {
        int tt = tid >> 4, j = tid & 15;
        float acc = 0.f;
#pragma unroll 8
        for (int r = 0; r < 48; ++r) acc = fmaf(w_to_mv[j * 48 + r], ybuf[tt][r], acc);
        int g = (j == 0) ? 0 : (j < 5) ? 1 : (j < 11) ? 2 : (j < 15) ? 3 : 4;
        acc *= w_equi[g];
        if (j == 0) acc += b_equi[0];
        mvbuf[tt][j] = acc;
    }
    __syncthreads();
    // C: z[tt][r] = gelu(sum_j w_from_mv[r][j]*mv[tt][j]) -> zbuf in A-fragment order
#pragma unroll
    for (int k = 0; k < 3; ++k) {
        int it = tid + k * 256;
        int tt = it / 48, r = it - tt * 48;
        float acc = 0.f;
#pragma unroll
        for (int j = 0; j < 16; ++j) acc = fmaf(w_from_mv[r * 16 + j], mvbuf[tt][j], acc);
        float z = gelu_exact(acc);
        int kt = r >> 5, qq = (r >> 3) & 3, jj = r & 7;
        zbuf[kt * 512 + (qq * 16 + tt) * 8 + jj] = f2bf(z);
    }
    __syncthreads();

    // ---------------- GEMM2 + epilogue: out = x + scale * (z @ w_up^T) ----------------
    const float scale = scale_p[0];
    short8 a0 = *(const short8*)&zbuf[lane * 8];
    short8 a1 = *(const short8*)&zbuf[512 + lane * 8];
    long rowbase = (token0 + q * 4) * D;
#pragma unroll 4
    for (int cc = 0; cc < 16; ++cc) {
        int cb = w * 16 + cc;
        short8 b0 = *(const short8*)(wup_b + (cb * 2 + 0) * 512 + lane * 8);
        short8 b1 = *(const short8*)(wup_b + (cb * 2 + 1) * 512 + lane * 8);
        float4a acc = {0.f, 0.f, 0.f, 0.f};
        acc = __builtin_amdgcn_mfma_f32_16x16x32_bf16(a0, b0, acc, 0, 0, 0);
        acc = __builtin_amdgcn_mfma_f32_16x16x32_bf16(a1, b1, acc, 0, 0, 0);
        int d = cb * 16 + m;
#pragma unroll
        for (int i = 0; i < 4; ++i) {
            int tok = q * 4 + i;
            float xv = bf2f(xsh[tok][d]);
            out[rowbase + (long)i * D + d] = fmaf(scale, acc[i], xv);
        }
    }
}

extern "C" void kernel_launch(void* const* d_in, const int* in_sizes, int n_in,
                              void* d_out, int out_size, void* d_ws, size_t ws_size,
                              hipStream_t stream) {
    const float* x         = (const float*)d_in[0];
    const float* gamma     = (const float*)d_in[1];
    const float* beta      = (const float*)d_in[2];
    const float* w_down    = (const float*)d_in[3];
    const float* w_to_mv   = (const float*)d_in[4];
    const float* w_equi    = (const float*)d_in[5];
    const float* b_equi    = (const float*)d_in[6];
    const float* w_from_mv = (const float*)d_in[7];
    const float* w_up      = (const float*)d_in[8];
    const float* scale_p   = (const float*)d_in[9];

    short* wdn_b = (short*)d_ws;          // 49152 bf16
    short* wup_b = wdn_b + 49152;         // 65536 bf16 (K padded to 64)

    prep_weights<<<448, 256, 0, stream>>>(w_down, w_up, wdn_b, wup_b);
    adapter_main<<<NTOK / TOKENS_PER_BLOCK, 256, 0, stream>>>(
        x, gamma, beta, w_to_mv, w_equi, b_equi, w_from_mv, scale_p,
        wdn_b, wup_b, (float*)d_out);
}

// Round 2
// 262.778 us; speedup vs baseline: 1.0264x; 1.0264x over previous
//
#include <hip/hip_runtime.h>
#include <hip/hip_bf16.h>

// LorentzEquivariantAdapter fused kernel, MI355X gfx950. Round 2.
// Key changes vs R1:
//  - LayerNorm affine folded into prepped GEMM1 weights:
//      y_r = rs*(x . (gamma*w_down_r)) + (-mu*rs)*c1_r + c2_r
//    so raw x (bf16) is the MFMA A operand -> no hln LDS buffer.
//  - LDS cut 78.3KB -> 39.3KB via scratch aliasing -> 4 blocks/CU.
//  - Phase 0 issues all 16 float4 loads before any use -> 16 outstanding/wave.

typedef __attribute__((ext_vector_type(8))) short short8;   // 8 bf16 = one MFMA A/B fragment
typedef __attribute__((ext_vector_type(4))) short short4b;  // 4 bf16 = 8B store
typedef __attribute__((ext_vector_type(4))) float float4a;  // MFMA accumulator

#define NTOK 32768
#define D 1024

__device__ __forceinline__ short f2bf(float x) {
    unsigned u = __float_as_uint(x);
    unsigned r = u + 0x7FFFu + ((u >> 16) & 1u);   // RNE
    return (short)(r >> 16);
}
__device__ __forceinline__ float bf2f(short s) {
    return __uint_as_float(((unsigned)(unsigned short)s) << 16);
}
__device__ __forceinline__ float gelu_exact(float v) {
    return 0.5f * v * (1.0f + erff(v * 0.70710678118654752f));
}

// ---- weight prep ----
// blocks [0,192):   wdn_b = bf16(gamma[d] * w_down[r][d]) in MFMA B-fragment order
// blocks [192,448): wup_b = bf16(w_up[d][r]) in MFMA B-fragment order, K padded 48->64
// blocks [448,496): c12[r] = sum_d gamma[d]*w_down[r][d];  c12[48+r] = sum_d beta[d]*w_down[r][d]
__global__ void prep_weights(const float* __restrict__ wdn_f, const float* __restrict__ wup_f,
                             const float* __restrict__ gamma, const float* __restrict__ beta,
                             short* __restrict__ wdn_b, short* __restrict__ wup_b,
                             float* __restrict__ c12) {
    int blk = blockIdx.x;
    int tid = threadIdx.x;
    if (blk < 192) {
        int o = blk * 256 + tid;
        int j = o & 7, lane = (o >> 3) & 63, kt = (o >> 9) & 31, cb = o >> 14;
        int r = cb * 16 + (lane & 15);
        int d = kt * 32 + (lane >> 4) * 8 + j;
        wdn_b[o] = f2bf(wdn_f[r * 1024 + d] * gamma[d]);
    } else if (blk < 448) {
        int o2 = (blk - 192) * 256 + tid;
        int j = o2 & 7, lane = (o2 >> 3) & 63, kt = (o2 >> 9) & 1, cb = o2 >> 10;
        int dcol = cb * 16 + (lane & 15);
        int r = kt * 32 + (lane >> 4) * 8 + j;
        wup_b[o2] = (r < 48) ? f2bf(wup_f[dcol * 48 + r]) : (short)0;
    } else {
        int r = blk - 448;                       // 0..47
        float a = 0.f, b = 0.f;
#pragma unroll
        for (int i = 0; i < 4; ++i) {
            int d = tid + 256 * i;
            float wv = wdn_f[r * 1024 + d];
            a = fmaf(wv, gamma[d], a);
            b = fmaf(wv, beta[d], b);
        }
#pragma unroll
        for (int off = 32; off; off >>= 1) {
            a += __shfl_xor(a, off);
            b += __shfl_xor(b, off);
        }
        __shared__ float red[8];
        int lane = tid & 63, w = tid >> 6;
        if (lane == 0) { red[w] = a; red[4 + w] = b; }
        __syncthreads();
        if (tid == 0) {
            c12[r]      = red[0] + red[1] + red[2] + red[3];
            c12[48 + r] = red[4] + red[5] + red[6] + red[7];
        }
    }
}

__launch_bounds__(256, 4)
__global__ void adapter_main(const float* __restrict__ x, const float* __restrict__ w_to_mv,
                             const float* __restrict__ w_equi, const float* __restrict__ b_equi,
                             const float* __restrict__ w_from_mv, const float* __restrict__ scale_p,
                             const short* __restrict__ wdn_b, const short* __restrict__ wup_b,
                             const float* __restrict__ c12, float* __restrict__ out) {
    // LDS total = 33024 + 6272 = 39296 B -> 4 blocks/CU
    __shared__ __align__(16) short xsh[16][1032];   // x as bf16, pad +8 shorts (A-fragment b128 reads)
    __shared__ __align__(16) float scratch[1568];
    // scratch layout (phase-aliased):
    //   [0..767]     ypart[0][tok][r]  ->  ybuf(gelu)  ->  zbuf shorts [0..1023] (=floats [0..511])
    //   [768..1535]  ypart[1][tok][r]  ->  mvbuf[tok][16] (floats [768..1023])
    //   [1536..1551] rs[tok]   [1552..1567] -mu*rs[tok]
    short* zbuf = (short*)scratch;

    const int tid  = threadIdx.x;
    const int lane = tid & 63;
    const int w    = tid >> 6;          // wave id 0..3
    const int q    = lane >> 4;         // MFMA quad
    const int m    = lane & 15;         // MFMA row/col within tile
    const long token0 = (long)blockIdx.x * 16;

    // ---------------- Phase 0: load x (16 loads in flight), stats, x->bf16 LDS ----------------
    {
        const float4* xr = (const float4*)(x + token0 * D);
        float4 v[16];
#pragma unroll
        for (int t = 0; t < 4; ++t)
#pragma unroll
            for (int i = 0; i < 4; ++i)
                v[t * 4 + i] = xr[(w * 4 + t) * 256 + lane + 64 * i];

#pragma unroll
        for (int t = 0; t < 4; ++t) {
            int tok = w * 4 + t;
            float s1 = 0.f, s2 = 0.f;
#pragma unroll
            for (int i = 0; i < 4; ++i) {
                float4 vv = v[t * 4 + i];
                s1 += vv.x + vv.y + vv.z + vv.w;
                s2 += vv.x * vv.x + vv.y * vv.y + vv.z * vv.z + vv.w * vv.w;
            }
#pragma unroll
            for (int off = 32; off; off >>= 1) {
                s1 += __shfl_xor(s1, off);
                s2 += __shfl_xor(s2, off);
            }
            float mu  = s1 * (1.0f / 1024.0f);
            float var = fmaf(-mu, mu, s2 * (1.0f / 1024.0f));
            float rs  = rsqrtf(var + 1e-5f);
#pragma unroll
            for (int i = 0; i < 4; ++i) {
                int d0 = 4 * lane + 256 * i;
                float4 vv = v[t * 4 + i];
                short4b xs = {f2bf(vv.x), f2bf(vv.y), f2bf(vv.z), f2bf(vv.w)};
                *(short4b*)&xsh[tok][d0] = xs;
            }
            if (lane == 0) {
                scratch[1536 + tok] = rs;
                scratch[1552 + tok] = -mu * rs;
            }
        }
    }
    __syncthreads();

    // ---------------- GEMM1: ypart = x_bf16 @ (gamma*w_down)^T, K split in halves ----------------
#pragma unroll
    for (int rep = 0; rep < 2; ++rep) {
        int jid = w + rep * 4;
        if (jid < 6) {
            int cb = jid % 3, kh = jid / 3;
            float4a acc = {0.f, 0.f, 0.f, 0.f};
            const short* bptr = wdn_b + ((cb * 32 + kh * 16) * 64 + lane) * 8;
            const short* aptr = &xsh[m][kh * 512 + q * 8];
#pragma unroll
            for (int kt = 0; kt < 16; ++kt) {
                short8 a = *(const short8*)(aptr + kt * 32);
                short8 b = *(const short8*)(bptr + kt * 512);
                acc = __builtin_amdgcn_mfma_f32_16x16x32_bf16(a, b, acc, 0, 0, 0);
            }
#pragma unroll
            for (int i = 0; i < 4; ++i)
                scratch[kh * 768 + (q * 4 + i) * 48 + cb * 16 + m] = acc[i];
        }
    }
    __syncthreads();

    // ---------------- Middle (fp32 VALU) ----------------
    // A: K-half reduce + LN affine correction + exact GELU (in place in ypart[0])
#pragma unroll
    for (int k = 0; k < 3; ++k) {
        int it = tid + k * 256;               // 768 = 16 tok x 48 r
        int tt = it / 48, r = it - tt * 48;
        float s = scratch[tt * 48 + r] + scratch[768 + tt * 48 + r];
        float y = fmaf(scratch[1536 + tt], s, fmaf(scratch[1552 + tt], c12[r], c12[48 + r]));
        scratch[tt * 48 + r] = gelu_exact(y);
    }
    __syncthreads();
    // B: multivectors + grade scale + scalar bias -> mvbuf (scratch[768..1023])
    {
        int tt = tid >> 4, j = tid & 15;
        float acc = 0.f;
#pragma unroll 8
        for (int r = 0; r < 48; ++r) acc = fmaf(w_to_mv[j * 48 + r], scratch[tt * 48 + r], acc);
        int g = (j == 0) ? 0 : (j < 5) ? 1 : (j < 11) ? 2 : (j < 15) ? 3 : 4;
        acc *= w_equi[g];
        if (j == 0) acc += b_equi[0];
        scratch[768 + tt * 16 + j] = acc;
    }
    __syncthreads();
    // C: z = gelu(mv @ w_from_mv^T) -> zbuf in GEMM2 A-fragment order (K padded 48->64)
#pragma unroll
    for (int k = 0; k < 3; ++k) {
        int it = tid + k * 256;
        int tt = it / 48, r = it - tt * 48;
        float acc = 0.f;
#pragma unroll
        for (int j = 0; j < 16; ++j) acc = fmaf(w_from_mv[r * 16 + j], scratch[768 + tt * 16 + j], acc);
        float z = gelu_exact(acc);
        int kt = r >> 5, qq = (r >> 3) & 3, jj = r & 7;
        zbuf[kt * 512 + (qq * 16 + tt) * 8 + jj] = f2bf(z);
    }
    zbuf[768 + tid] = 0;                      // K padding 48..63
    __syncthreads();

    // ---------------- GEMM2 + epilogue: out = x + scale * (z @ w_up^T) ----------------
    const float scale = scale_p[0];
    short8 a0 = *(const short8*)&zbuf[lane * 8];
    short8 a1 = *(const short8*)&zbuf[512 + lane * 8];
    long rowbase = (token0 + q * 4) * D;
#pragma unroll 4
    for (int cc = 0; cc < 16; ++cc) {
        int cb = w * 16 + cc;
        short8 b0 = *(const short8*)(wup_b + (cb * 2 + 0) * 512 + lane * 8);
        short8 b1 = *(const short8*)(wup_b + (cb * 2 + 1) * 512 + lane * 8);
        float4a acc = {0.f, 0.f, 0.f, 0.f};
        acc = __builtin_amdgcn_mfma_f32_16x16x32_bf16(a0, b0, acc, 0, 0, 0);
        acc = __builtin_amdgcn_mfma_f32_16x16x32_bf16(a1, b1, acc, 0, 0, 0);
        int d = cb * 16 + m;
#pragma unroll
        for (int i = 0; i < 4; ++i) {
            int tok = q * 4 + i;
            float xv = bf2f(xsh[tok][d]);
            out[rowbase + (long)i * D + d] = fmaf(scale, acc[i], xv);
        }
    }
}

extern "C" void kernel_launch(void* const* d_in, const int* in_sizes, int n_in,
                              void* d_out, int out_size, void* d_ws, size_t ws_size,
                              hipStream_t stream) {
    const float* x         = (const float*)d_in[0];
    const float* gamma     = (const float*)d_in[1];
    const float* beta      = (const float*)d_in[2];
    const float* w_down    = (const float*)d_in[3];
    const float* w_to_mv   = (const float*)d_in[4];
    const float* w_equi    = (const float*)d_in[5];
    const float* b_equi    = (const float*)d_in[6];
    const float* w_from_mv = (const float*)d_in[7];
    const float* w_up      = (const float*)d_in[8];
    const float* scale_p   = (const float*)d_in[9];

    short* wdn_b = (short*)d_ws;               // 49152 bf16
    short* wup_b = wdn_b + 49152;              // 65536 bf16 (K padded to 64)
    float* c12   = (float*)(wup_b + 65536);    // 96 fp32

    prep_weights<<<496, 256, 0, stream>>>(w_down, w_up, gamma, beta, wdn_b, wup_b, c12);
    adapter_main<<<NTOK / 16, 256, 0, stream>>>(
        x, w_to_mv, w_equi, b_equi, w_from_mv, scale_p,
        wdn_b, wup_b, c12, (float*)d_out);
}